// Round 1
// baseline (433.260 us; speedup 1.0000x reference)
//
#include <hip/hip_runtime.h>

// QRegulariser: theta = hidden[B,H] @ W[Q,H]^T + b;  out = mean(1 - prod_q cos^2(theta_q/2))
// B=65536, H=1024, Q=8. HBM-bound: must stream 256 MB of hidden exactly once.
//
// Layout: block = 256 threads = 4 waves; 64 rows/block; each wave owns one
// 256-wide h-segment of all 64 rows. Rows staged via LDS (padded stride 36
// floats -> conflict-free b128) so global loads are coalesced while W loads
// are wave-uniform (scalar s_load broadcast, no VGPR cost).

#define HDIM 1024
#define QN 8
#define RPB 64          // rows per block
#define SEGS 4          // h segments == waves per block
#define SEG_H 256       // h per segment
#define CHUNK 32        // h per round
#define ROUNDS 8        // SEG_H / CHUNK
#define ROW_STRIDE 36   // CHUNK + 4 pad floats (144 B, 16B-aligned rows)

__global__ __launch_bounds__(256, 4)
void qreg_kernel(const float* __restrict__ hidden,
                 const float* __restrict__ W,
                 const float* __restrict__ bias,
                 float* __restrict__ out) {
    __shared__ __align__(16) float tile[SEGS * RPB * ROW_STRIDE]; // 36864 B

    const int tid  = threadIdx.x;
    const int lane = tid & 63;
    const int seg  = __builtin_amdgcn_readfirstlane(tid >> 6); // wave-uniform SGPR
    const int row_base = blockIdx.x * RPB;

    // staging coords: 8 threads cover one row-chunk (8 x float4 = 32 floats)
    const int s_row = (tid >> 3) & 7; // 0..7 (+8*i)
    const int s_col = tid & 7;        // 0..7

    const float* gbase = hidden + (size_t)row_base * HDIM + seg * SEG_H + s_col * 4;

    float4 stage[8];
#pragma unroll
    for (int i = 0; i < 8; ++i) {
        stage[i] = *reinterpret_cast<const float4*>(gbase + (size_t)(s_row + 8 * i) * HDIM);
    }

    float acc[QN];
#pragma unroll
    for (int q = 0; q < QN; ++q) acc[q] = 0.f;

#pragma unroll
    for (int k = 0; k < ROUNDS; ++k) {
        // stage this round's tile into LDS (conflict-free: bank grp = (row+col)%8)
#pragma unroll
        for (int i = 0; i < 8; ++i) {
            int r = s_row + 8 * i;
            *reinterpret_cast<float4*>(&tile[(seg * RPB + r) * ROW_STRIDE + s_col * 4]) = stage[i];
        }
        __syncthreads();

        // prefetch next round's global data while computing this round
        if (k < ROUNDS - 1) {
#pragma unroll
            for (int i = 0; i < 8; ++i) {
                stage[i] = *reinterpret_cast<const float4*>(
                    gbase + (size_t)(s_row + 8 * i) * HDIM + (k + 1) * CHUNK);
            }
        }

        // compute: this thread owns row `lane` of its wave's segment
        const float* xrow = &tile[(seg * RPB + lane) * ROW_STRIDE];
        const int hbase = seg * SEG_H + k * CHUNK;
#pragma unroll
        for (int j = 0; j < CHUNK / 4; ++j) {
            float4 x = *reinterpret_cast<const float4*>(&xrow[j * 4]);
#pragma unroll
            for (int q = 0; q < QN; ++q) {
                const float* wq = W + q * HDIM + hbase + j * 4; // wave-uniform -> s_load
                acc[q] += x.x * wq[0] + x.y * wq[1] + x.z * wq[2] + x.w * wq[3];
            }
        }
        __syncthreads();
    }

    // combine the 4 segment-partials per row via LDS, then finish on wave 0
    float* red = tile; // 4*64*8 floats, safe after final sync
#pragma unroll
    for (int q = 0; q < QN; ++q)
        red[(seg * RPB + lane) * QN + q] = acc[q];
    __syncthreads();

    if (seg == 0) {
        float p0 = 1.f;
#pragma unroll
        for (int q = 0; q < QN; ++q) {
            float th = red[(0 * RPB + lane) * QN + q]
                     + red[(1 * RPB + lane) * QN + q]
                     + red[(2 * RPB + lane) * QN + q]
                     + red[(3 * RPB + lane) * QN + q]
                     + bias[q];
            float c = __cosf(0.5f * th);
            p0 *= c * c;
        }
        float contrib = 1.f - p0;
#pragma unroll
        for (int off = 32; off > 0; off >>= 1)
            contrib += __shfl_down(contrib, off);
        if (lane == 0)
            atomicAdd(out, contrib * (1.0f / 65536.0f));
    }
}

extern "C" void kernel_launch(void* const* d_in, const int* in_sizes, int n_in,
                              void* d_out, int out_size, void* d_ws, size_t ws_size,
                              hipStream_t stream) {
    const float* hidden = (const float*)d_in[0];
    const float* W      = (const float*)d_in[1];
    const float* bias   = (const float*)d_in[2];
    float* out          = (float*)d_out;

    hipMemsetAsync(out, 0, sizeof(float), stream);
    qreg_kernel<<<65536 / RPB, 256, 0, stream>>>(hidden, W, bias, out);
}

// Round 2
// 364.067 us; speedup vs baseline: 1.1901x; 1.1901x over previous
//
#include <hip/hip_runtime.h>

// QRegulariser: theta = hidden[B,H] @ W[Q,H]^T + b;  out = mean(1 - prod_q cos^2(theta_q/2))
// B=65536, H=1024, Q=8.  HBM-bound: stream 256 MB of hidden exactly once.
//
// R1 design: block = 1024 threads (16 waves), 64 rows/block.  Each round
// stages a 256-float chunk of all 64 rows via global_load_lds width=16:
// one instruction = one contiguous 1 KB row-chunk (perfect DRAM page
// locality), zero staging VGPRs (no spill possible).  Wave w computes
// h-slice [16w,16w+16) of the chunk for row `lane` -> W offsets are
// wave-uniform -> scalar s_loads.  LDS row stride 260 floats: ds_read_b128
// bank rotation 4/row -> 2-way aliasing only (free).

#define HDIM 1024
#define QN 8
#define RPB 64           // rows per block
#define CHUNK 256        // floats per row per round (1 KB)
#define ROUNDS 4         // HDIM / CHUNK
#define ROW_STRIDE 260   // floats: 1 KB chunk + 16 B pad

__global__ __launch_bounds__(1024, 8)
void qreg_kernel(const float* __restrict__ hidden,
                 const float* __restrict__ W,
                 const float* __restrict__ bias,
                 float* __restrict__ out) {
    __shared__ __align__(16) float tile[RPB * ROW_STRIDE]; // 66560 B -> 2 blocks/CU

    const int tid  = threadIdx.x;
    const int lane = tid & 63;
    const int w    = __builtin_amdgcn_readfirstlane(tid >> 6); // wave id 0..15
    const size_t row_base = (size_t)blockIdx.x * RPB;

    float acc[QN];
#pragma unroll
    for (int q = 0; q < QN; ++q) acc[q] = 0.f;

#pragma unroll
    for (int k = 0; k < ROUNDS; ++k) {
        // stage: wave w DMAs rows 4w..4w+3, chunk k (1 KB contiguous each)
#pragma unroll
        for (int i = 0; i < 4; ++i) {
            const int r = 4 * w + i;
            const float* g = hidden + (row_base + r) * HDIM + k * CHUNK + lane * 4;
            __builtin_amdgcn_global_load_lds(
                (const __attribute__((address_space(1))) void*)g,
                (__attribute__((address_space(3))) void*)&tile[r * ROW_STRIDE],
                16, 0, 0);
        }
        __syncthreads();

        // compute: this thread owns row `lane`, h-slice [16w, 16w+16) of chunk k
        float4 x0 = *reinterpret_cast<const float4*>(&tile[lane * ROW_STRIDE + w * 16 + 0]);
        float4 x1 = *reinterpret_cast<const float4*>(&tile[lane * ROW_STRIDE + w * 16 + 4]);
        float4 x2 = *reinterpret_cast<const float4*>(&tile[lane * ROW_STRIDE + w * 16 + 8]);
        float4 x3 = *reinterpret_cast<const float4*>(&tile[lane * ROW_STRIDE + w * 16 + 12]);

        const float* wbase = W + k * CHUNK + w * 16; // wave-uniform -> s_load
#pragma unroll
        for (int q = 0; q < QN; ++q) {
            const float* wq = wbase + q * HDIM;
            acc[q] += x0.x * wq[0]  + x0.y * wq[1]  + x0.z * wq[2]  + x0.w * wq[3]
                    + x1.x * wq[4]  + x1.y * wq[5]  + x1.z * wq[6]  + x1.w * wq[7]
                    + x2.x * wq[8]  + x2.y * wq[9]  + x2.z * wq[10] + x2.w * wq[11]
                    + x3.x * wq[12] + x3.y * wq[13] + x3.z * wq[14] + x3.w * wq[15];
        }
        __syncthreads(); // next round overwrites tile
    }

    // ---- epilogue: combine 16 wave-partials per row ----
    // part[w][lane][q], stride 9 to break bank alignment
    float* part = tile; // 16*64*9 = 9216 floats, fits
#pragma unroll
    for (int q = 0; q < QN; ++q)
        part[(w * RPB + lane) * 9 + q] = acc[q];
    __syncthreads();

    float* theta = tile + 9216; // 64*8 floats
    if (tid < 512) {
        const int r = tid >> 3, q = tid & 7;
        float th = bias[q];
#pragma unroll
        for (int ww = 0; ww < 16; ++ww)
            th += part[(ww * RPB + r) * 9 + q];
        theta[r * 8 + q] = th;
    }
    __syncthreads();

    if (tid < 64) {
        float p0 = 1.f;
#pragma unroll
        for (int q = 0; q < QN; ++q) {
            float c = __cosf(0.5f * theta[tid * 8 + q]);
            p0 *= c * c;
        }
        float contrib = 1.f - p0;
#pragma unroll
        for (int off = 32; off > 0; off >>= 1)
            contrib += __shfl_down(contrib, off);
        if (tid == 0)
            atomicAdd(out, contrib * (1.0f / 65536.0f));
    }
}

extern "C" void kernel_launch(void* const* d_in, const int* in_sizes, int n_in,
                              void* d_out, int out_size, void* d_ws, size_t ws_size,
                              hipStream_t stream) {
    const float* hidden = (const float*)d_in[0];
    const float* W      = (const float*)d_in[1];
    const float* bias   = (const float*)d_in[2];
    float* out          = (float*)d_out;

    hipMemsetAsync(out, 0, sizeof(float), stream);
    qreg_kernel<<<65536 / RPB, 1024, 0, stream>>>(hidden, W, bias, out);
}